// Round 1
// baseline (503.634 us; speedup 1.0000x reference)
//
#include <hip/hip_runtime.h>

#define ROW_LEN 16384
#define THREADS 256
#define ITERS (ROW_LEN / (THREADS * 4))   // 16
#define NBINS 2048
#define CAP 1024
#define MBCAP 128
#define TPRE 2.5f        // pre-filter; E[count]≈204/row for N(0,1). Fallback covers all data.

typedef float f4v __attribute__((ext_vector_type(4)));

// Composite key: larger |x| first, then lower index (jax.lax.top_k tie-break).
__device__ __forceinline__ unsigned long long make_key(unsigned abits, unsigned idx) {
    return ((unsigned long long)abits << 32) | (unsigned)(~idx);
}

// Find boundary bin b: count(bins>b)=g < kk <= g+hist[b]. Barrier before+after inside.
__device__ __forceinline__ void find_boundary(const unsigned* hist, unsigned kk,
                                              int* s_b, unsigned* s_g, unsigned* wtot) {
    const int t = threadIdx.x;
    const int lane = t & 63;
    const int w = t >> 6;
    unsigned s_own = 0;
    #pragma unroll
    for (int i = 0; i < 8; ++i) s_own += hist[t * 8 + i];
    unsigned acc = s_own;                       // wave inclusive suffix scan
    #pragma unroll
    for (int off = 1; off < 64; off <<= 1) {
        unsigned v = __shfl_down(acc, off);
        if (lane + off < 64) acc += v;
    }
    if (lane == 0) wtot[w] = acc;
    __syncthreads();
    unsigned addw = 0;
    #pragma unroll
    for (int w2 = 0; w2 < THREADS / 64; ++w2) if (w2 > w) addw += wtot[w2];
    unsigned above = acc - s_own + addw;        // strictly above my 8-bin group
    #pragma unroll
    for (int i = 7; i >= 0; --i) {
        unsigned h = hist[t * 8 + i];
        if (above < kk && above + h >= kk) { *s_b = t * 8 + i; *s_g = above; }
        above += h;
    }
    __syncthreads();
}

__global__ __launch_bounds__(THREADS, 4)
void topk_act_kernel(const float* __restrict__ x, const int* __restrict__ kptr,
                     float* __restrict__ out)
{
    const int t = threadIdx.x;
    const long long row = blockIdx.x;
    const f4v* __restrict__ xv = (const f4v*)(x + row * ROW_LEN);
    f4v* __restrict__ ov = (f4v*)(out + row * ROW_LEN);

    const int k = *kptr;
    if (k <= 0) {
        f4v z = (f4v)(0.0f);
        #pragma unroll
        for (int j = 0; j < ITERS; ++j)
            __builtin_nontemporal_store(z, &ov[j * THREADS + t]);
        return;
    }
    const unsigned kk = (unsigned)(k < ROW_LEN ? k : ROW_LEN);

    __shared__ unsigned hist[NBINS];
    __shared__ unsigned long long lst[CAP];
    __shared__ unsigned long long lst2[MBCAP];
    __shared__ unsigned wtot[THREADS / 64];
    __shared__ unsigned s_cnt, s_cnt2;
    __shared__ int s_b;
    __shared__ unsigned s_g;
    __shared__ unsigned long long s_ccut;

    // ---- issue the whole row slice as 16 independent NT loads (deep ILP hides
    //      HBM latency; values stay register-resident for the rest of the kernel,
    //      eliminating the second read entirely) ----
    f4v vals[ITERS];                 // 64 VGPRs; all indexing below is compile-time
    #pragma unroll
    for (int it = 0; it < ITERS; ++it)
        vals[it] = __builtin_nontemporal_load(&xv[it * THREADS + t]);

    // overlap LDS init with the loads in flight
    #pragma unroll
    for (int i = 0; i < NBINS / THREADS; ++i) hist[i * THREADS + t] = 0u;
    if (t == 0) { s_cnt = 0u; s_cnt2 = 0u; }
    __syncthreads();

    // ---- candidate pre-filter from registers ----
    const unsigned abs_pre = __float_as_uint(TPRE);
    #pragma unroll
    for (int it = 0; it < ITERS; ++it) {
        #pragma unroll
        for (int c = 0; c < 4; ++c) {
            unsigned ab = __float_as_uint(vals[it][c]) & 0x7fffffffu;
            if (ab >= abs_pre) {                      // ~1.2% of elements
                unsigned p = atomicAdd(&s_cnt, 1u);
                if (p < CAP) {
                    unsigned idx = (unsigned)((it * THREADS + t) * 4 + c);
                    lst[p] = make_key(ab, idx);
                }
            }
        }
    }
    __syncthreads();

    const unsigned m_all = s_cnt;

    if (m_all >= kk && m_all <= CAP) {
        // ---- fast path: kk-th largest key lies inside lst (hist pre-zeroed) ----
        for (unsigned e = t; e < m_all; e += THREADS) {
            float a = __uint_as_float((unsigned)(lst[e] >> 32));
            int rb = (int)((a - TPRE) * 1024.0f);       // bins over [2.5, 4.5)
            rb = rb > (NBINS - 1) ? (NBINS - 1) : rb;
            atomicAdd(&hist[rb], 1u);
        }
        __syncthreads();
        find_boundary(hist, kk, &s_b, &s_g, wtot);
        const int bsel = s_b;
        const unsigned r = kk - s_g;                    // r-th largest within bin bsel
        for (unsigned e = t; e < m_all; e += THREADS) { // gather boundary bin (tiny)
            unsigned long long key = lst[e];
            float a = __uint_as_float((unsigned)(key >> 32));
            int rb = (int)((a - TPRE) * 1024.0f);
            rb = rb > (NBINS - 1) ? (NBINS - 1) : rb;
            if (rb == bsel) {
                unsigned p = atomicAdd(&s_cnt2, 1u);
                if (p < MBCAP) lst2[p] = key;
            }
        }
        __syncthreads();
        const unsigned mb = s_cnt2;
        if (mb <= MBCAP) {
            for (unsigned e = t; e < mb; e += THREADS) {
                unsigned long long ce = lst2[e];
                unsigned rank = 0;
                for (unsigned q = 0; q < mb; ++q) rank += (lst2[q] > ce) ? 1u : 0u;
                if (rank == r - 1) s_ccut = ce;          // unique: keys distinct
            }
        } else {                                         // overflow: rank vs full list
            for (unsigned e = t; e < m_all; e += THREADS) {
                unsigned long long ce = lst[e];
                float a = __uint_as_float((unsigned)(ce >> 32));
                int rb = (int)((a - TPRE) * 1024.0f);
                rb = rb > (NBINS - 1) ? (NBINS - 1) : rb;
                if (rb == bsel) {
                    unsigned rank = 0;
                    for (unsigned q = 0; q < m_all; ++q) {
                        unsigned long long kq = lst[q];
                        float aq = __uint_as_float((unsigned)(kq >> 32));
                        int rbq = (int)((aq - TPRE) * 1024.0f);
                        rbq = rbq > (NBINS - 1) ? (NBINS - 1) : rbq;
                        rank += (rbq == bsel && kq > ce) ? 1u : 0u;
                    }
                    if (rank == r - 1) s_ccut = ce;
                }
            }
        }
        __syncthreads();
    } else {
        // ---- fallback (never taken for N(0,1) data; guarantees correctness) ----
        // hist is still all-zero here (fast path never ran). Use s_cnt2 (still 0)
        // as the gather counter: avoids resetting s_cnt (read/reset race on the
        // branch condition) entirely.
        #pragma unroll
        for (int it = 0; it < ITERS; ++it) {
            #pragma unroll
            for (int c = 0; c < 4; ++c) {
                float a = fabsf(vals[it][c]);
                int bin = (int)(a * 256.0f);             // bins over [0, 8)
                bin = bin > (NBINS - 1) ? (NBINS - 1) : bin;
                atomicAdd(&hist[bin], 1u);
            }
        }
        __syncthreads();
        find_boundary(hist, kk, &s_b, &s_g, wtot);
        const int b = s_b;
        unsigned r = kk - s_g;
        #pragma unroll
        for (int it = 0; it < ITERS; ++it) {             // gather bin-b keys from regs
            #pragma unroll
            for (int c = 0; c < 4; ++c) {
                unsigned ab = __float_as_uint(vals[it][c]) & 0x7fffffffu;
                float a = __uint_as_float(ab);
                int bin = (int)(a * 256.0f);
                bin = bin > (NBINS - 1) ? (NBINS - 1) : bin;
                if (bin == b) {
                    unsigned p = atomicAdd(&s_cnt2, 1u);
                    if (p < CAP) {
                        unsigned idx = (unsigned)((it * THREADS + t) * 4 + c);
                        lst[p] = make_key(ab, idx);
                    }
                }
            }
        }
        __syncthreads();
        const unsigned mbf = s_cnt2 < CAP ? s_cnt2 : CAP;
        if (r > mbf) r = mbf;
        for (unsigned e = t; e < mbf; e += THREADS) {
            unsigned long long ce = lst[e];
            unsigned rank = 0;
            for (unsigned q = 0; q < mbf; ++q) rank += (lst[q] > ce) ? 1u : 0u;
            if (rank == r - 1) s_ccut = ce;
        }
        __syncthreads();
    }

    const unsigned long long cc = s_ccut;
    const unsigned cut_hi = (unsigned)(cc >> 32);
    const unsigned cut_lo = (unsigned)cc;                // == ~cut_idx

    // ---- masked write straight from registers (no re-read) ----
    #pragma unroll
    for (int it = 0; it < ITERS; ++it) {
        f4v w;
        #pragma unroll
        for (int c = 0; c < 4; ++c) {
            unsigned ab = __float_as_uint(vals[it][c]) & 0x7fffffffu;
            unsigned idx = (unsigned)((it * THREADS + t) * 4 + c);
            bool keep = (ab > cut_hi) | ((ab == cut_hi) & (~idx >= cut_lo));
            w[c] = keep ? vals[it][c] : 0.0f;
        }
        __builtin_nontemporal_store(w, &ov[it * THREADS + t]);
    }
}

extern "C" void kernel_launch(void* const* d_in, const int* in_sizes, int n_in,
                              void* d_out, int out_size, void* d_ws, size_t ws_size,
                              hipStream_t stream) {
    const float* x  = (const float*)d_in[0];
    const int*   kp = (const int*)d_in[1];
    float* out = (float*)d_out;
    const int rows = out_size / ROW_LEN;   // 4096
    topk_act_kernel<<<dim3(rows), dim3(THREADS), 0, stream>>>(x, kp, out);
}

// Round 4
// 471.032 us; speedup vs baseline: 1.0692x; 1.0692x over previous
//
#include <hip/hip_runtime.h>

#define ROW_LEN 16384
#define THREADS 512
#define ITERS (ROW_LEN / (THREADS * 4))   // 8
#define NWAVES (THREADS / 64)             // 8
#define NBINS 2048
#define BPT (NBINS / THREADS)             // 4 bins per thread
#define CAP 1024
#define MBCAP 128
#define TPRE 2.5f        // pre-filter; E[count]≈204/row for N(0,1). Fallback covers all data.

typedef float f4v __attribute__((ext_vector_type(4)));

// Composite key: larger |x| first, then lower index (jax.lax.top_k tie-break).
__device__ __forceinline__ unsigned long long make_key(unsigned abits, unsigned idx) {
    return ((unsigned long long)abits << 32) | (unsigned)(~idx);
}

// Find boundary bin b: count(bins>b)=g < kk <= g+hist[b]. Barrier before+after inside.
__device__ __forceinline__ void find_boundary(const unsigned* hist, unsigned kk,
                                              int* s_b, unsigned* s_g, unsigned* wtot) {
    const int t = threadIdx.x;
    const int lane = t & 63;
    const int w = t >> 6;
    unsigned s_own = 0;
    #pragma unroll
    for (int i = 0; i < BPT; ++i) s_own += hist[t * BPT + i];
    unsigned acc = s_own;                       // wave inclusive suffix scan
    #pragma unroll
    for (int off = 1; off < 64; off <<= 1) {
        unsigned v = __shfl_down(acc, off);
        if (lane + off < 64) acc += v;
    }
    if (lane == 0) wtot[w] = acc;
    __syncthreads();
    unsigned addw = 0;
    #pragma unroll
    for (int w2 = 0; w2 < NWAVES; ++w2) if (w2 > w) addw += wtot[w2];
    unsigned above = acc - s_own + addw;        // strictly above my BPT-bin group
    #pragma unroll
    for (int i = BPT - 1; i >= 0; --i) {
        unsigned h = hist[t * BPT + i];
        if (above < kk && above + h >= kk) { *s_b = t * BPT + i; *s_g = above; }
        above += h;
    }
    __syncthreads();
}

__global__ __launch_bounds__(THREADS)
void topk_act_kernel(const float* __restrict__ x, const int* __restrict__ kptr,
                     float* __restrict__ out)
{
    const int t = threadIdx.x;
    const long long row = blockIdx.x;
    const f4v* __restrict__ xv = (const f4v*)(x + row * ROW_LEN);
    f4v* __restrict__ ov = (f4v*)(out + row * ROW_LEN);

    const int k = *kptr;
    if (k <= 0) {
        f4v z = (f4v)(0.0f);
        #pragma unroll
        for (int j = 0; j < ITERS; ++j)
            __builtin_nontemporal_store(z, &ov[j * THREADS + t]);
        return;
    }
    const unsigned kk = (unsigned)(k < ROW_LEN ? k : ROW_LEN);

    __shared__ unsigned hist[NBINS];
    __shared__ unsigned long long lst[CAP];
    __shared__ unsigned long long lst2[MBCAP];
    __shared__ unsigned wtot[NWAVES];
    __shared__ unsigned s_cnt, s_cnt2;
    __shared__ int s_b;
    __shared__ unsigned s_g;
    __shared__ unsigned long long s_ccut;

    // ---- issue the whole per-thread row slice as 8 independent NT loads.
    //      32 VGPRs for vals @512 threads: total demand ~80 regs -> no spill,
    //      deep ILP hides HBM latency, values stay register-resident so the
    //      output pass needs no re-read. ----
    f4v vals[ITERS];                 // all indexing below is compile-time
    #pragma unroll
    for (int it = 0; it < ITERS; ++it)
        vals[it] = __builtin_nontemporal_load(&xv[it * THREADS + t]);

    // overlap LDS init with the loads in flight
    #pragma unroll
    for (int i = 0; i < NBINS / THREADS; ++i) hist[i * THREADS + t] = 0u;
    if (t == 0) { s_cnt = 0u; s_cnt2 = 0u; }
    __syncthreads();

    // ---- candidate pre-filter from registers ----
    const unsigned abs_pre = __float_as_uint(TPRE);
    #pragma unroll
    for (int it = 0; it < ITERS; ++it) {
        #pragma unroll
        for (int c = 0; c < 4; ++c) {
            unsigned ab = __float_as_uint(vals[it][c]) & 0x7fffffffu;
            if (ab >= abs_pre) {                      // ~1.2% of elements
                unsigned p = atomicAdd(&s_cnt, 1u);
                if (p < CAP) {
                    unsigned idx = (unsigned)((it * THREADS + t) * 4 + c);
                    lst[p] = make_key(ab, idx);
                }
            }
        }
    }
    __syncthreads();

    const unsigned m_all = s_cnt;

    if (m_all >= kk && m_all <= CAP) {
        // ---- fast path: kk-th largest key lies inside lst (hist pre-zeroed) ----
        for (unsigned e = t; e < m_all; e += THREADS) {
            float a = __uint_as_float((unsigned)(lst[e] >> 32));
            int rb = (int)((a - TPRE) * 1024.0f);       // bins over [2.5, 4.5)
            rb = rb > (NBINS - 1) ? (NBINS - 1) : rb;
            atomicAdd(&hist[rb], 1u);
        }
        __syncthreads();
        find_boundary(hist, kk, &s_b, &s_g, wtot);
        const int bsel = s_b;
        const unsigned r = kk - s_g;                    // r-th largest within bin bsel
        for (unsigned e = t; e < m_all; e += THREADS) { // gather boundary bin (tiny)
            unsigned long long key = lst[e];
            float a = __uint_as_float((unsigned)(key >> 32));
            int rb = (int)((a - TPRE) * 1024.0f);
            rb = rb > (NBINS - 1) ? (NBINS - 1) : rb;
            if (rb == bsel) {
                unsigned p = atomicAdd(&s_cnt2, 1u);
                if (p < MBCAP) lst2[p] = key;
            }
        }
        __syncthreads();
        const unsigned mb = s_cnt2;
        if (mb <= MBCAP) {
            for (unsigned e = t; e < mb; e += THREADS) {
                unsigned long long ce = lst2[e];
                unsigned rank = 0;
                for (unsigned q = 0; q < mb; ++q) rank += (lst2[q] > ce) ? 1u : 0u;
                if (rank == r - 1) s_ccut = ce;          // unique: keys distinct
            }
        } else {                                         // overflow: rank vs full list
            for (unsigned e = t; e < m_all; e += THREADS) {
                unsigned long long ce = lst[e];
                float a = __uint_as_float((unsigned)(ce >> 32));
                int rb = (int)((a - TPRE) * 1024.0f);
                rb = rb > (NBINS - 1) ? (NBINS - 1) : rb;
                if (rb == bsel) {
                    unsigned rank = 0;
                    for (unsigned q = 0; q < m_all; ++q) {
                        unsigned long long kq = lst[q];
                        float aq = __uint_as_float((unsigned)(kq >> 32));
                        int rbq = (int)((aq - TPRE) * 1024.0f);
                        rbq = rbq > (NBINS - 1) ? (NBINS - 1) : rbq;
                        rank += (rbq == bsel && kq > ce) ? 1u : 0u;
                    }
                    if (rank == r - 1) s_ccut = ce;
                }
            }
        }
        __syncthreads();
    } else {
        // ---- fallback (never taken for N(0,1) data; guarantees correctness) ----
        // hist is still all-zero here (fast path never ran). Use s_cnt2 (still 0)
        // as the gather counter: avoids resetting s_cnt (read/reset race on the
        // branch condition) entirely.
        #pragma unroll
        for (int it = 0; it < ITERS; ++it) {
            #pragma unroll
            for (int c = 0; c < 4; ++c) {
                float a = fabsf(vals[it][c]);
                int bin = (int)(a * 256.0f);             // bins over [0, 8)
                bin = bin > (NBINS - 1) ? (NBINS - 1) : bin;
                atomicAdd(&hist[bin], 1u);
            }
        }
        __syncthreads();
        find_boundary(hist, kk, &s_b, &s_g, wtot);
        const int b = s_b;
        unsigned r = kk - s_g;
        #pragma unroll
        for (int it = 0; it < ITERS; ++it) {             // gather bin-b keys from regs
            #pragma unroll
            for (int c = 0; c < 4; ++c) {
                unsigned ab = __float_as_uint(vals[it][c]) & 0x7fffffffu;
                float a = __uint_as_float(ab);
                int bin = (int)(a * 256.0f);
                bin = bin > (NBINS - 1) ? (NBINS - 1) : bin;
                if (bin == b) {
                    unsigned p = atomicAdd(&s_cnt2, 1u);
                    if (p < CAP) {
                        unsigned idx = (unsigned)((it * THREADS + t) * 4 + c);
                        lst[p] = make_key(ab, idx);
                    }
                }
            }
        }
        __syncthreads();
        const unsigned mbf = s_cnt2 < CAP ? s_cnt2 : CAP;
        if (r > mbf) r = mbf;
        for (unsigned e = t; e < mbf; e += THREADS) {
            unsigned long long ce = lst[e];
            unsigned rank = 0;
            for (unsigned q = 0; q < mbf; ++q) rank += (lst[q] > ce) ? 1u : 0u;
            if (rank == r - 1) s_ccut = ce;
        }
        __syncthreads();
    }

    const unsigned long long cc = s_ccut;
    const unsigned cut_hi = (unsigned)(cc >> 32);
    const unsigned cut_lo = (unsigned)cc;                // == ~cut_idx

    // ---- masked write straight from registers (no re-read) ----
    #pragma unroll
    for (int it = 0; it < ITERS; ++it) {
        f4v w;
        #pragma unroll
        for (int c = 0; c < 4; ++c) {
            unsigned ab = __float_as_uint(vals[it][c]) & 0x7fffffffu;
            unsigned idx = (unsigned)((it * THREADS + t) * 4 + c);
            bool keep = (ab > cut_hi) | ((ab == cut_hi) & (~idx >= cut_lo));
            w[c] = keep ? vals[it][c] : 0.0f;
        }
        __builtin_nontemporal_store(w, &ov[it * THREADS + t]);
    }
}

extern "C" void kernel_launch(void* const* d_in, const int* in_sizes, int n_in,
                              void* d_out, int out_size, void* d_ws, size_t ws_size,
                              hipStream_t stream) {
    const float* x  = (const float*)d_in[0];
    const int*   kp = (const int*)d_in[1];
    float* out = (float*)d_out;
    const int rows = out_size / ROW_LEN;   // 4096
    topk_act_kernel<<<dim3(rows), dim3(THREADS), 0, stream>>>(x, kp, out);
}